// Round 13
// baseline (99.231 us; speedup 1.0000x reference)
//
#include <hip/hip_runtime.h>
#include <cstdint>

// ---------------------------------------------------------------------------
// MXFP linear w/ MSD(NAF) truncation — round 10 (3rd resubmit; broker timeout).
//
// Math (validated R1/R4/R9, absmax 2^-7):
//   x_q = sgn*mx*2^(ex-3), w_q = sgn*mw*2^(ew-3), mx,mw in {0,8..15}.
//   trunc(prod,eff) = sgn * R(2*mx*mw, eff) * 2^(ex+ew-7)
//   R = NAF trunc: p=mx*mw, s3=3p, c=s3^p, wd=32-clz(c),
//       drop=med3(wd-eff,0,wd), kc=(-1<<drop)&c, r=(s3&kc)-(p&kc).
//   contribution = r * fxs * fws;  fxs=sgn*xs*2^ex, fws=sgn*ws*2^(ew-7).
//   eff = budget - di;  budget = 14 - emax(n,o) + floor(lx_b+lw_b).
//   PROVED (R10-R13): intra e_max_block == 0 always — argmax elem of each
//   block is exactly +-1.0 after the self-division, and no |xn|<=1 element
//   can quantize above 1.0; so di = min(-e,63) with NO wave reduction.
//
// R10 vs R9 (measured: total 98us; main <40us now below the harness's 40us
// 268MB ws-poison fills in top-5; fixed overhead ~55us/iter):
//  1. main: 8 outs/wave, 32-out x 32-k blocks (KS=32, one scale-block per
//     chunk) -> 16 products per prefetch group (2x ILP cover), half the
//     global xa loads, single budget set per wave.
//  2. prep: 2nd shfl reduction removed (see proof above).
//  3. reduce sums 32 partials (part = 8MB of the 268MB ws).
// ---------------------------------------------------------------------------

#define NN 128
#define KF 1024
#define OF 512
#define NB 32
#define KS 32           // K-split: 32 chunks x 32 k (exactly one block)

// ws layout (16B-aligned offsets):
//   xaP   @ 0        1 MB   (512 kp x 128 n x 16B; 2 k-elems per uint4)
//   wB    @ 1048576  4 MB   (512 o x 1024 k x 8B: fws bits, mw)
//   lxT   @ 5242880  16 KB  (32 b x 128 n)
//   lw    @ 5259264  64 KB  (512 o x 32 b)
//   emaxT @ 5324800  256 KB (512 o x 128 n)
//   part  @ 5580800  8 MB   (32 s x 512 o x 128 n f32)

__global__ __launch_bounds__(256) void prep_kernel(
    const float* __restrict__ x, const float* __restrict__ w,
    uint2* __restrict__ xaP2, uint2* __restrict__ wB,
    float* __restrict__ lxT, float* __restrict__ lw) {
  int bid = blockIdx.x;
  int tid = (int)threadIdx.x;
  bool is_x = bid < 512;
  int eid = is_x ? bid * 256 + tid : (bid - 512) * 256 + tid;
  float v = is_x ? x[eid] : w[eid];
  float a = fabsf(v);
  float m = a;
  #pragma unroll
  for (int s = 1; s < 32; s <<= 1) m = fmaxf(m, __shfl_xor(m, s, 32));
  float scale = fmaxf(m, 1e-30f);
  float xn = v / scale;                       // IEEE-exact division
  unsigned nb_ = __float_as_uint(xn);
  unsigned ab = nb_ & 0x7fffffffu;
  bool zz = ab < 0x00800000u;                 // zero (subnormals impossible)
  int e = (int)(ab >> 23) - 127;
  // mantissa in [1,2) exactly; mi = round-half-even(mant*8) in [8,16]
  float am = __uint_as_float((ab & 0x007fffffu) | 0x3f800000u);
  int mi = (int)rintf(am * 8.0f);
  if (mi == 16) { mi = 8; ++e; }              // renormalize
  if (zz) mi = 0;
  unsigned sgn = nb_ & 0x80000000u;
  unsigned sb = __float_as_uint(scale);
  if (is_x) {
    // e_max_block == 0 always (argmax element is exactly +-1.0) -> di = -e.
    int di = zz ? 63 : min(-e, 63);
    unsigned fb = zz ? 0u : ((sb + (((unsigned)e) << 23)) | sgn);
    unsigned meta = (unsigned)mi | ((unsigned)di << 8);
    int k = eid & 1023, n = eid >> 10;
    xaP2[((k >> 1) * NN + n) * 2 + (k & 1)] = make_uint2(fb, meta);
    if ((tid & 31) == 0) lxT[(k >> 5) * NN + n] = log2f(scale);
  } else {
    unsigned fb = zz ? 0u : ((sb + (((unsigned)(e - 7)) << 23)) | sgn);
    wB[eid] = make_uint2(fb, (unsigned)mi);
    int o = eid >> 10, k = eid & 1023;
    if ((tid & 31) == 0) lw[o * NB + (k >> 5)] = log2f(scale);
  }
}

__global__ __launch_bounds__(256) void emax_kernel(
    const float* __restrict__ lxT, const float* __restrict__ lw,
    float* __restrict__ emaxT) {
  int gid = blockIdx.x * 256 + (int)threadIdx.x;   // 65536
  int n = gid & (NN - 1), o = gid >> 7;
  float m = -1e30f;
  #pragma unroll
  for (int b = 0; b < NB; ++b)
    m = fmaxf(m, floorf(lxT[b * NN + n] + lw[o * NB + b]));
  emaxT[o * NN + n] = m;
}

// one product: ~15 VALU ops
__device__ __forceinline__ void prod_acc(int mx, int di, float fxs,
                                         unsigned fwbits, int mw, int nb,
                                         float& acc) {
  int p  = __mul24(mx, mw);                 // <= 225
  int s3 = (p << 1) + p;                    // 3p (v_lshl_add)
  int cx = s3 ^ p;                          // NAF digit positions of q=2p
  int wd = 32 - __clz(cx);                  // width; cx==0 -> 0
  int u  = wd + di + nb;                    // v_add3 (nb = -budget)
  int drop = min(max(u, 0), wd);            // v_med3_i32
  unsigned keep = 0xFFFFFFFFu << drop;
  unsigned kc = keep & (unsigned)cx;
  int r = (int)((unsigned)s3 & kc) - (int)((unsigned)p & kc);
  acc = fmaf((float)r * fxs, __uint_as_float(fwbits), acc);
}

// grid 1024 = s(32 K-chunks) x og(16 groups of 32 outs) x ng(2);
// 256 thr; wave w4 owns 8 outs.
__global__ __launch_bounds__(256, 4) void main_kernel(
    const uint4* __restrict__ xaP, const uint2* __restrict__ wB,
    const float* __restrict__ lxT, const float* __restrict__ lw,
    const float* __restrict__ emaxT, float* __restrict__ part) {
  __shared__ __align__(16) uint2 tile[32 * 32 + 2];  // 8KB + pad (g=16 read)
  int bid = blockIdx.x;
  int s   = bid & 31;
  int og  = (bid >> 5) & 15;
  int ng  = bid >> 9;
  int tid = (int)threadIdx.x, lane = tid & 63, w4 = tid >> 6;
  int o_base = og * 32;
  int k0 = s * 32;
  int n = ng * 64 + lane;

  // stage 32 outs x 32 k of wB (8KB): 8 threads/row, 2 uint4 each
  {
    int r = tid >> 3, c = tid & 7;
    const uint4* src = reinterpret_cast<const uint4*>(&wB[(o_base + r) * KF + k0]);
    uint4* dst = reinterpret_cast<uint4*>(&tile[r * 32]);
    dst[c] = src[c];
    dst[c + 8] = src[c + 8];
  }

  int ow = o_base + w4 * 8;
  float lxv = lxT[s * NN + n];
  float acc[8];
  int nbv[8];
  #pragma unroll
  for (int j = 0; j < 8; ++j) {
    acc[j] = 0.f;
    float em = emaxT[(ow + j) * NN + n];
    nbv[j] = -(int)(14.0f - em + floorf(lxv + lw[(ow + j) * NB + s]));
  }
  __syncthreads();

  const uint4* xaRow = &xaP[(size_t)(k0 >> 1) * NN + n];
#define LDT(j, g) (*reinterpret_cast<const uint4*>(&tile[(w4 * 8 + (j)) * 32 + 2 * (g)]))
#define COMPUTE(xv, T)                                                     \
  {                                                                        \
    int mx0 = (int)(xv.y & 255u), di0 = (int)(xv.y >> 8);                  \
    int mx1 = (int)(xv.w & 255u), di1 = (int)(xv.w >> 8);                  \
    float fx0 = __uint_as_float(xv.x), fx1 = __uint_as_float(xv.z);        \
    _Pragma("unroll")                                                      \
    for (int j = 0; j < 8; ++j) {                                          \
      prod_acc(mx0, di0, fx0, T[j].x, (int)T[j].y, nbv[j], acc[j]);        \
      prod_acc(mx1, di1, fx1, T[j].z, (int)T[j].w, nbv[j], acc[j]);        \
    }                                                                      \
  }

  // prologue: group 0 into the A buffers
  uint4 xa_ = xaRow[0];
  uint4 ta[8], tb[8];
  #pragma unroll
  for (int j = 0; j < 8; ++j) ta[j] = LDT(j, 0);

  #pragma unroll 1
  for (int g2 = 0; g2 < 8; ++g2) {
    int gb = 2 * g2 + 1;
    // prefetch odd group into B
    uint4 xb_ = xaRow[(size_t)gb * NN];
    #pragma unroll
    for (int j = 0; j < 8; ++j) tb[j] = LDT(j, gb);
    COMPUTE(xa_, ta);
    // prefetch next even group into A (g=16 on last iter: OOB-safe —
    // xaP overflow lands at wB base (still inside ws); tile pad covers it)
    int gc = gb + 1;
    xa_ = xaRow[(size_t)gc * NN];
    #pragma unroll
    for (int j = 0; j < 8; ++j) ta[j] = LDT(j, gc);
    COMPUTE(xb_, tb);
  }

  #pragma unroll
  for (int j = 0; j < 8; ++j)
    part[((size_t)(s * OF) + ow + j) * NN + n] = acc[j];
#undef COMPUTE
#undef LDT
}

__global__ __launch_bounds__(256) void reduce_kernel(
    const float* __restrict__ part, const float* __restrict__ bias,
    float* __restrict__ out) {
  int gid = blockIdx.x * 256 + (int)threadIdx.x;   // 65536
  int n = gid & (NN - 1), o = gid >> 7;
  float sum = bias[o];
  #pragma unroll
  for (int c = 0; c < KS; ++c) sum += part[((size_t)c * OF + o) * NN + n];
  out[n * OF + o] = sum;
}

extern "C" void kernel_launch(void* const* d_in, const int* in_sizes, int n_in,
                              void* d_out, int out_size, void* d_ws, size_t ws_size,
                              hipStream_t stream) {
  const float* x    = (const float*)d_in[0];
  const float* w    = (const float*)d_in[1];
  const float* bias = (const float*)d_in[2];
  float* out = (float*)d_out;
  char* ws = (char*)d_ws;
  uint2* xaP2  = (uint2*)(ws);
  uint4* xaP   = (uint4*)(ws);
  uint2* wB    = (uint2*)(ws + 1048576);
  float* lxT   = (float*)(ws + 5242880);
  float* lw    = (float*)(ws + 5259264);
  float* emaxT = (float*)(ws + 5324800);
  float* part  = (float*)(ws + 5580800);

  prep_kernel<<<2560, 256, 0, stream>>>(x, w, xaP2, wB, lxT, lw);
  emax_kernel<<<256, 256, 0, stream>>>(lxT, lw, emaxT);
  main_kernel<<<1024, 256, 0, stream>>>(xaP, wB, lxT, lw, emaxT, part);
  reduce_kernel<<<256, 256, 0, stream>>>(part, bias, out);
}